// Round 6
// baseline (1078.425 us; speedup 1.0000x reference)
//
#include <hip/hip_runtime.h>
#include <stdint.h>

#define C_CH   64
#define H_IN   200
#define W_IN   320
#define H_OUT  48
#define W_OUT  320
#define N_BOX  256

typedef float float4v __attribute__((ext_vector_type(4), aligned(16)));

// R0 (measured-best regime: grid (64,256) channel-fastest, 320 thr, monolithic
// LDS tile, reg-staged dwordx4 loads, conflict-free scalar gather, nt dword
// stores) with ONE change: stage only the bbox sub-rectangle --
// nur = min(h,48) unique rows x K4 (<=80) float4-cols -- distributed over ALL
// 320 threads with full-width dwordx4 loads (unlike R3, whose t<K4 staging
// crippled issue width and confounded the read-volume test).
//
// Packed LDS layout [nur][K4] float4s; LDS write addr = p*16 (p = staged
// float4 index). p -> (row, wrd) via exact umulhi reciprocal (p < 2^12,
// K4 < 2^7: error < p/2^32 -> floor exact), no runtime division per element.
//
// Row slots: h<=48 -> slot s holds input row y0+s, gather slot = i*h/48;
//            h> 48 -> slot s=i holds row y0+i*h/48 (all 48 distinct), gather
//            slot = i.
// Gather: lane col-step <= 1, row term uniform -> conflict-free.
//
// Avg staged bytes/block ~ 0.28x of full-width (1.0 GB -> ~0.28 GB chipwide):
// a clean single-variable test of whether L2/L3-served read volume shares the
// ~4.9 TB/s combined fabric budget with the 983 MB write stream.
__global__ __launch_bounds__(320) void roi_crop_kernel(
    const float* __restrict__ x,
    const int*   __restrict__ bboxes,
    const int*   __restrict__ box_img,
    float*       __restrict__ out)
{
    __shared__ __align__(16) float tile[H_OUT * W_OUT];   // 61,440 B worst case

    const int c   = blockIdx.x;   // channel 0..63 (fastest -> contiguous output regions)
    const int box = blockIdx.y;   // box 0..255
    const int t   = threadIdx.x;  // 0..319

    const int4 bb = *(const int4*)(bboxes + box * 4);
    int x0 = min(max(bb.x, 0), W_IN - 1);
    int y0 = min(max(bb.y, 0), H_IN - 1);
    int x1 = min(max(bb.z, 0), W_IN - 1);
    int y1 = min(max(bb.w, 0), H_IN - 1);
    x1 = max(x1, x0);
    y1 = max(y1, y0);

    const int h   = y1 - y0 + 1;
    const int w   = x1 - x0 + 1;
    const int img = box_img[box];

    const float* __restrict__ plane_in =
        x + ((size_t)img * C_CH + c) * (H_IN * W_IN);
    float* __restrict__ plane_out =
        out + ((size_t)box * C_CH + c) * (H_OUT * W_OUT);

    const int  x0f4    = x0 >> 2;                  // first staged float4-col
    const int  K4      = (x1 >> 2) - x0f4 + 1;     // float4s per staged row, 1..80
    const int  x0f     = x0f4 << 2;                // first staged float col (16B-aligned)
    const bool small_h = (h <= H_OUT);
    const int  nur     = small_h ? h : H_OUT;      // unique rows staged
    const uint32_t total = (uint32_t)(nur * K4);   // staged float4s, <= 3840

    // Exact reciprocal for p/K4 (p < 4096, K4 < 128): inv = ceil(2^32/K4).
    const uint32_t inv = (K4 > 1)
        ? (uint32_t)((0x100000000ULL + (uint32_t)K4 - 1) / (uint32_t)K4) : 0u;

    // ---- Phase 1: stage sub-rect, all 320 threads, dwordx4, <=12 each.
    float4v v[12];
    #pragma unroll
    for (int k = 0; k < 12; ++k) {
        const uint32_t p = (uint32_t)t + (uint32_t)k * 320u;
        if (p < total) {
            const uint32_t row = (K4 == 1) ? p : __umulhi(p, inv);
            const uint32_t wrd = p - row * (uint32_t)K4;
            const int r = small_h ? (y0 + (int)row)
                                  : (y0 + ((int)row * h) / H_OUT);
            v[k] = *(const float4v*)(plane_in + (size_t)r * W_IN + x0f + (wrd << 2));
        }
    }
    #pragma unroll
    for (int k = 0; k < 12; ++k) {
        const uint32_t p = (uint32_t)t + (uint32_t)k * 320u;
        if (p < total)
            *(float4v*)&tile[p << 2] = v[k];      // packed [nur][K4] layout
    }
    __syncthreads();

    // ---- Phase 2: conflict-free scalar gather + contiguous nt store (R0 verbatim).
    const int ldrow = K4 << 2;                    // floats per staged row
    const int cadj  = (x0 + (t * w) / W_OUT) - x0f;  // lane step <= 1
    #pragma unroll 8
    for (int i = 0; i < H_OUT; ++i) {
        const int s   = small_h ? (i * h) / H_OUT : i;   // uniform across lanes
        const float val = tile[s * ldrow + cadj];
        __builtin_nontemporal_store(val, plane_out + i * W_OUT + t);
    }
}

extern "C" void kernel_launch(void* const* d_in, const int* in_sizes, int n_in,
                              void* d_out, int out_size, void* d_ws, size_t ws_size,
                              hipStream_t stream) {
    const float* x       = (const float*)d_in[0];
    const int*   bboxes  = (const int*)d_in[1];
    const int*   box_img = (const int*)d_in[2];
    float*       out     = (float*)d_out;

    dim3 grid(C_CH, N_BOX);   // (64, 256) = 16,384 blocks, channel fastest
    dim3 block(320);
    roi_crop_kernel<<<grid, block, 0, stream>>>(x, bboxes, box_img, out);
}